// Round 1
// baseline (6274.192 us; speedup 1.0000x reference)
//
#include <hip/hip_runtime.h>
#include <hip/hip_bf16.h>
#include <stdint.h>

typedef float  f32x4  __attribute__((ext_vector_type(4)));
typedef short  bf16x8 __attribute__((ext_vector_type(8)));
typedef unsigned int  u32;
typedef unsigned short u16;

#define BS    64
#define SEQ   1024
#define HID   512

// ---------- helpers ----------
__device__ __forceinline__ u16 f2bf(float f) {
    u32 u = __float_as_uint(f);
    u32 r = (u + 0x7FFFu + ((u >> 16) & 1u)) >> 16;   // RNE
    return (u16)r;
}
__device__ __forceinline__ float bf2f(u16 h) {
    return __uint_as_float(((u32)h) << 16);
}
__device__ __forceinline__ u32 pk2(float a, float b) {
    return (u32)f2bf(a) | ((u32)f2bf(b) << 16);
}
__device__ __forceinline__ float sigm(float x)  { return 1.f / (1.f + __expf(-x)); }
__device__ __forceinline__ float tanh_(float x) { return 1.f - 2.f / (1.f + __expf(2.f * x)); }

// ---------- ws layout ----------
// [0, 2MB)            w4t  bf16 [2048][512]
// [2MB, +8KB)         b4   f32  [2048]
// [.., +4KB)          flags int [4][16]
// [.., +128KB)        hbuf u32  [2][4][16][256]   (2x bf16 packed)
// [.., +128KB)        cbuf f32  [4][16][512]
// [4MB, ...)          xp   bf16 [64*Tc][2048]
#define OFF_W4T   0
#define OFF_B4    (2u*1024*1024)
#define OFF_FLAGS (OFF_B4 + 8192)
#define OFF_HBUF  (OFF_FLAGS + 4096)
#define OFF_CBUF  (OFF_HBUF + 131072)
#define OFF_XP    (4u*1024*1024)

// ---------- pack W / bias ----------
__global__ void pack_w(const float* __restrict__ Wi, const float* __restrict__ Wf,
                       const float* __restrict__ Wc, const float* __restrict__ Wo,
                       const float* __restrict__ bi, const float* __restrict__ bf_,
                       const float* __restrict__ bc, const float* __restrict__ bo,
                       u16* __restrict__ w4t, float* __restrict__ b4) {
    int n = blockIdx.x;                 // 0..2047
    int gate = n >> 9, c = n & 511;
    const float* W = (gate == 0) ? Wi : (gate == 1) ? Wf : (gate == 2) ? Wc : Wo;
    const float* B = (gate == 0) ? bi : (gate == 1) ? bf_ : (gate == 2) ? bc : bo;
    int k = threadIdx.x * 2;            // 2 per thread
    u32 v = pk2(W[(size_t)k * 512 + c], W[(size_t)(k + 1) * 512 + c]);
    *(u32*)&w4t[(size_t)n * 512 + k] = v;
    if (threadIdx.x == 0) b4[n] = B[c];
}

// ---------- projection GEMM:  xp[m][n] = bf16( x_row(m) . w4t[n] + b4[n] ) ----------
__global__ __launch_bounds__(256, 2)
void gemm_proj(const float* __restrict__ x, const u16* __restrict__ w4t,
               const float* __restrict__ b4, u16* __restrict__ xp,
               int t0, int Tc) {
    __shared__ __align__(16) u16 lA[128 * 64];
    __shared__ __align__(16) u16 lB[128 * 64];

    int ntb = blockIdx.x & 15;
    int mb  = blockIdx.x >> 4;
    int tps = Tc >> 7;                       // tiles per batch strip
    int bstrip = mb / tps, tb = mb % tps;
    const float* Abase = x + (size_t)(bstrip * SEQ + t0 + tb * 128) * 512;
    size_t xprow0 = (size_t)bstrip * Tc + tb * 128;
    int n0 = ntb * 128;

    int tid = threadIdx.x, lane = tid & 63, w = tid >> 6;
    int wm = w >> 1, wn = w & 1;

    f32x4 acc[4][4];
#pragma unroll
    for (int a = 0; a < 4; a++)
#pragma unroll
        for (int b = 0; b < 4; b++) acc[a][b] = (f32x4){0.f, 0.f, 0.f, 0.f};

    for (int kb = 0; kb < 8; kb++) {
        // stage A (fp32 -> bf16)
        {
            int row = tid >> 1, half = tid & 1;
            const float* src = Abase + (size_t)row * 512 + kb * 64 + half * 32;
            u32 tmp[16];
#pragma unroll
            for (int q = 0; q < 8; q++) {
                float4 f = *(const float4*)(src + q * 4);
                tmp[q * 2]     = pk2(f.x, f.y);
                tmp[q * 2 + 1] = pk2(f.z, f.w);
            }
            u16* dst = &lA[row * 64 + half * 32];
#pragma unroll
            for (int q = 0; q < 4; q++)
                *(uint4*)(dst + q * 8) = *(uint4*)&tmp[q * 4];
        }
        // stage B (already bf16)
        {
            int row = tid >> 1, kc = (tid & 1) * 32;
            const u16* src = w4t + (size_t)(n0 + row) * 512 + kb * 64 + kc;
            uint4 v0 = *(const uint4*)(src);
            uint4 v1 = *(const uint4*)(src + 8);
            uint4 v2 = *(const uint4*)(src + 16);
            uint4 v3 = *(const uint4*)(src + 24);
            u16* dst = &lB[row * 64 + kc];
            *(uint4*)(dst) = v0; *(uint4*)(dst + 8) = v1;
            *(uint4*)(dst + 16) = v2; *(uint4*)(dst + 24) = v3;
        }
        __syncthreads();
#pragma unroll
        for (int kt = 0; kt < 2; kt++) {
            bf16x8 a[4], bb[4];
#pragma unroll
            for (int mt = 0; mt < 4; mt++)
                a[mt] = *(const bf16x8*)&lA[(wm * 64 + mt * 16 + (lane & 15)) * 64 + kt * 32 + (lane >> 4) * 8];
#pragma unroll
            for (int nt = 0; nt < 4; nt++)
                bb[nt] = *(const bf16x8*)&lB[(wn * 64 + nt * 16 + (lane & 15)) * 64 + kt * 32 + (lane >> 4) * 8];
#pragma unroll
            for (int mt = 0; mt < 4; mt++)
#pragma unroll
                for (int nt = 0; nt < 4; nt++)
                    acc[mt][nt] = __builtin_amdgcn_mfma_f32_16x16x32_bf16(a[mt], bb[nt], acc[mt][nt], 0, 0, 0);
        }
        __syncthreads();
    }
    // epilogue: + bias, store bf16
#pragma unroll
    for (int nt = 0; nt < 4; nt++) {
        int n = n0 + wn * 64 + nt * 16 + (lane & 15);
        float bv = b4[n];
#pragma unroll
        for (int mt = 0; mt < 4; mt++)
#pragma unroll
            for (int r = 0; r < 4; r++) {
                size_t m = xprow0 + wm * 64 + mt * 16 + (lane >> 4) * 4 + r;
                xp[m * 2048 + n] = f2bf(acc[mt][nt][r] + bv);
            }
    }
}

// ---------- recurrence ----------
// 64 WGs: gid = blockIdx>>4 (batch group of 16), s = blockIdx&15 (32 h-cols / 128 z-cols)
// wave w <-> gate w. U slice persistent in VGPRs (32 bf16x8 frags / lane).
__global__ __launch_bounds__(256, 1)
void lstm_rec(const float* __restrict__ U0, const float* __restrict__ U1,
              const float* __restrict__ U2, const float* __restrict__ U3,
              const u16* __restrict__ xp, float* __restrict__ out,
              u32* __restrict__ hbuf, int* __restrict__ flags,
              float* __restrict__ cbuf, int t0, int Tc) {
    const int gid = blockIdx.x >> 4;
    const int s   = blockIdx.x & 15;
    const int tid = threadIdx.x;
    const int w = tid >> 6, lane = tid & 63;

    __shared__ __align__(16) u16  h_lds[16 * 512];     // swizzled
    __shared__ float z_lds[4][16][33];                 // [gate][b][col] (+pad)
    __shared__ float c_lds[16][32];

    // ---- load persistent U fragments (gate = wave) ----
    const float* Ug = (w == 0) ? U0 : (w == 1) ? U1 : (w == 2) ? U2 : U3;
    bf16x8 ub[16][2];
#pragma unroll
    for (int kt = 0; kt < 16; kt++)
#pragma unroll
        for (int nt = 0; nt < 2; nt++) {
            int col = s * 32 + nt * 16 + (lane & 15);
            int kbase = kt * 32 + (lane >> 4) * 8;
            union { short sh[8]; bf16x8 v; } uu;
#pragma unroll
            for (int j = 0; j < 8; j++)
                uu.sh[j] = (short)f2bf(Ug[(size_t)(kbase + j) * 512 + col]);
            ub[kt][nt] = uu.v;
        }

    // ---- init c ----
    {
        int b = tid >> 4, cp = tid & 15;
        if (t0 == 0) {
            c_lds[b][2 * cp] = 0.f; c_lds[b][2 * cp + 1] = 0.f;
        } else {
            float2 cv = *(const float2*)&cbuf[((size_t)gid * 16 + b) * 512 + s * 32 + 2 * cp];
            c_lds[b][2 * cp] = cv.x; c_lds[b][2 * cp + 1] = cv.y;
        }
    }
    __syncthreads();

    for (int tl = 0; tl < Tc; tl++) {
        const int t = t0 + tl;

        // 1. prefetch xp (independent of h)
        u16 xr[2][4];
#pragma unroll
        for (int nt = 0; nt < 2; nt++)
#pragma unroll
            for (int r = 0; r < 4; r++) {
                int b = (lane >> 4) * 4 + r;
                int zc = (w << 9) + s * 32 + nt * 16 + (lane & 15);
                xr[nt][r] = xp[(size_t)((gid * 16 + b) * Tc + tl) * 2048 + zc];
            }

        // 2. wait for all 16 producers of h_{t-1}
        if (w == 0 && lane < 16) {
            while (__hip_atomic_load(&flags[gid * 16 + lane], __ATOMIC_RELAXED,
                                     __HIP_MEMORY_SCOPE_AGENT) < t)
                __builtin_amdgcn_s_sleep(1);
        }
        __syncthreads();

        // 3. load h_{t-1} (bf16-packed) -> swizzled LDS
        {
            int row = tid >> 4, chunk = tid & 15;
            u32* src = hbuf + (size_t)((t - 1) & 1) * 16384 + gid * 4096 + row * 256 + chunk * 16;
            u32 v[16];
#pragma unroll
            for (int i = 0; i < 16; i++)
                v[i] = __hip_atomic_load(src + i, __ATOMIC_RELAXED, __HIP_MEMORY_SCOPE_AGENT);
#pragma unroll
            for (int q = 0; q < 4; q++) {
                u32 byte = row * 1024 + chunk * 64 + q * 16;
                byte ^= (u32)(row & 7) << 4;
                uint4 vv; vv.x = v[q*4]; vv.y = v[q*4+1]; vv.z = v[q*4+2]; vv.w = v[q*4+3];
                *(uint4*)((char*)h_lds + byte) = vv;
            }
        }
        __syncthreads();

        // 4. z = h @ U (per-gate wave), + xp
        f32x4 acc0 = (f32x4){0.f,0.f,0.f,0.f}, acc1 = (f32x4){0.f,0.f,0.f,0.f};
#pragma unroll
        for (int kt = 0; kt < 16; kt++) {
            u32 byte = (u32)(lane & 15) * 1024 + kt * 64 + (lane >> 4) * 16;
            byte ^= (u32)((lane & 15) & 7) << 4;
            bf16x8 af = *(const bf16x8*)((const char*)h_lds + byte);
            acc0 = __builtin_amdgcn_mfma_f32_16x16x32_bf16(af, ub[kt][0], acc0, 0, 0, 0);
            acc1 = __builtin_amdgcn_mfma_f32_16x16x32_bf16(af, ub[kt][1], acc1, 0, 0, 0);
        }
#pragma unroll
        for (int r = 0; r < 4; r++) { acc0[r] += bf2f(xr[0][r]); acc1[r] += bf2f(xr[1][r]); }

        // 5. share z across gates
#pragma unroll
        for (int r = 0; r < 4; r++) {
            z_lds[w][(lane >> 4) * 4 + r][lane & 15]      = acc0[r];
            z_lds[w][(lane >> 4) * 4 + r][16 + (lane & 15)] = acc1[r];
        }
        __syncthreads();

        // 6. gates + state update (2 cols / thread)
        {
            int b = tid >> 4, cp = tid & 15;
            float zi0 = z_lds[0][b][2*cp], zi1 = z_lds[0][b][2*cp+1];
            float zf0 = z_lds[1][b][2*cp], zf1 = z_lds[1][b][2*cp+1];
            float zc0 = z_lds[2][b][2*cp], zc1 = z_lds[2][b][2*cp+1];
            float zo0 = z_lds[3][b][2*cp], zo1 = z_lds[3][b][2*cp+1];
            float c0 = c_lds[b][2*cp], c1 = c_lds[b][2*cp+1];

            float i0 = fmaxf(zi0, 0.f), i1 = fmaxf(zi1, 0.f);
            float f0 = fmaxf(zf0, 0.f), f1 = fmaxf(zf1, 0.f);
            float g0 = tanh_(zc0), g1 = tanh_(zc1);
            float o0 = sigm(zo0),  o1 = sigm(zo1);
            c0 = f0 * c0 + i0 * g0;
            c1 = f1 * c1 + i1 * g1;
            float h0 = o0 * tanh_(c0), h1 = o1 * tanh_(c1);
            c_lds[b][2*cp] = c0; c_lds[b][2*cp+1] = c1;

            // output (fp32)
            float2 hv; hv.x = h0; hv.y = h1;
            *(float2*)&out[(size_t)((gid * 16 + b) * SEQ + t) * 512 + s * 32 + 2 * cp] = hv;

            // h exchange (bf16 packed, agent scope)
            __hip_atomic_store(hbuf + (size_t)(t & 1) * 16384 + gid * 4096 + b * 256 + s * 16 + cp,
                               pk2(h0, h1), __ATOMIC_RELAXED, __HIP_MEMORY_SCOPE_AGENT);
        }
        __syncthreads();   // drains vmcnt: all 256 threads' h stores complete

        // 7. publish
        if (tid == 0)
            __hip_atomic_store(&flags[gid * 16 + s], t + 1, __ATOMIC_RELEASE,
                               __HIP_MEMORY_SCOPE_AGENT);
    }

    // save c for next chunk
    {
        int b = tid >> 4, cp = tid & 15;
        float2 cv; cv.x = c_lds[b][2*cp]; cv.y = c_lds[b][2*cp+1];
        *(float2*)&cbuf[((size_t)gid * 16 + b) * 512 + s * 32 + 2 * cp] = cv;
    }
}

// ---------- launch ----------
extern "C" void kernel_launch(void* const* d_in, const int* in_sizes, int n_in,
                              void* d_out, int out_size, void* d_ws, size_t ws_size,
                              hipStream_t stream) {
    const float* x  = (const float*)d_in[0];
    const float* Wg[4] = {(const float*)d_in[1], (const float*)d_in[4],
                          (const float*)d_in[7], (const float*)d_in[10]};
    const float* Ug[4] = {(const float*)d_in[2], (const float*)d_in[5],
                          (const float*)d_in[8], (const float*)d_in[11]};
    const float* Bg[4] = {(const float*)d_in[3], (const float*)d_in[6],
                          (const float*)d_in[9], (const float*)d_in[12]};
    float* out = (float*)d_out;

    char* ws = (char*)d_ws;
    u16*   w4t   = (u16*)(ws + OFF_W4T);
    float* b4    = (float*)(ws + OFF_B4);
    int*   flags = (int*)(ws + OFF_FLAGS);
    u32*   hbuf  = (u32*)(ws + OFF_HBUF);
    float* cbuf  = (float*)(ws + OFF_CBUF);
    u16*   xp    = (u16*)(ws + OFF_XP);

    // pick chunk length that fits ws
    int Tc = 128;
    for (int c = 1024; c >= 128; c >>= 1)
        if ((size_t)OFF_XP + (size_t)BS * c * 2048 * 2 <= ws_size) { Tc = c; break; }

    // zero flags + h double-buffer (h_{-1} = 0)
    hipMemsetAsync(ws + OFF_FLAGS, 0, 4096 + 131072, stream);

    pack_w<<<2048, 256, 0, stream>>>(Wg[0], Wg[1], Wg[2], Wg[3],
                                     Bg[0], Bg[1], Bg[2], Bg[3], w4t, b4);

    for (int t0 = 0; t0 < SEQ; t0 += Tc) {
        dim3 ggrid((unsigned)(BS * (Tc / 128) * 16));
        gemm_proj<<<ggrid, 256, 0, stream>>>(x, w4t, b4, xp, t0, Tc);
        lstm_rec<<<64, 256, 0, stream>>>(Ug[0], Ug[1], Ug[2], Ug[3],
                                         xp, out, hbuf, flags, cbuf, t0, Tc);
    }
}